// Round 5
// baseline (230.670 us; speedup 1.0000x reference)
//
#include <hip/hip_runtime.h>

// ---------------------------------------------------------------------------
// CovariateAttention: out = MHA_causal(rope(x@Wq^T), rope(x@Wk^T), x@Wv^T) @ Wo^T
// B=2, S=2048, E=d_attn=1024, H=16, hd=64. All GEMM-shaped work in bf16 MFMA.
// ---------------------------------------------------------------------------

typedef float  f32x4  __attribute__((ext_vector_type(4)));
typedef short  short8 __attribute__((ext_vector_type(8)));

#define MFMA16(a,b,c) __builtin_amdgcn_mfma_f32_16x16x32_bf16((a),(b),(c),0,0,0)
// async global->LDS DMA, 16B/lane; LDS dest = wave-uniform base + lane*16
#define GLD_LDS16(g, l)                                                        \
  __builtin_amdgcn_global_load_lds(                                            \
      (const __attribute__((address_space(1))) unsigned int*)(g),              \
      (__attribute__((address_space(3))) unsigned int*)(l), 16, 0, 0)

__device__ __forceinline__ unsigned short f2bf(float f) {
  unsigned int x = __float_as_uint(f);
  x += 0x7fffu + ((x >> 16) & 1u);          // RNE
  return (unsigned short)(x >> 16);
}
__device__ __forceinline__ float bf2f(unsigned short u) {
  return __uint_as_float(((unsigned int)u) << 16);
}

// ---------------------------------------------------------------------------
// Kernel 1: convert x (4M fp32) + Wq,Wk,Wv,Wo (1M each) to bf16 (contiguous).
// ---------------------------------------------------------------------------
__global__ __launch_bounds__(256) void cvt_all(const float* __restrict__ x,
                                               const float* __restrict__ wq,
                                               const float* __restrict__ wk,
                                               const float* __restrict__ wv,
                                               const float* __restrict__ wo,
                                               ushort* __restrict__ dst) {
  const int i = blockIdx.x * 256 + threadIdx.x;      // [0, 2M)
  const float* src;
  int off;
  if (i < 1048576) { src = x; off = i; }
  else {
    const int j = i - 1048576;
    const int wsel = j >> 18;
    off = j & 262143;
    src = (wsel == 0) ? wq : (wsel == 1) ? wk : (wsel == 2) ? wv : wo;
  }
  const float4 v = ((const float4*)src)[off];
  ushort4 o = make_ushort4(f2bf(v.x), f2bf(v.y), f2bf(v.z), f2bf(v.w));
  ((ushort4*)dst)[i] = o;
}

// ---------------------------------------------------------------------------
// GEMM (m97 pattern): C[m,n] = sum_k A[m,k]*B[n,k]. BM=128 x BN tile, BK=32,
// 256 thr = 4 waves (2x2), wave tile 64 x BN/2. global_load_lds width=16
// staging, unpadded LDS stride 32, 2-barrier K-loop.
// BN=128 for the fused QKV GEMM; BN=64 for out-proj (N=1024 -> 512 blocks,
// 2 blocks/CU instead of 1 — latency hiding).
// ---------------------------------------------------------------------------
template<int MODE, int BN>
__global__ __launch_bounds__(256) void gemm_bt(const ushort* __restrict__ A,
                                               const ushort* __restrict__ B,
                                               void* __restrict__ Cv,
                                               int K) {
  constexpr int NI = BN / 32;               // n-frags per wave (4 or 2)
  __shared__ __align__(16) short As[128 * 32];
  __shared__ __align__(16) short Bs[BN * 32];
  const int tid  = threadIdx.x;
  const int lane = tid & 63, w = tid >> 6;
  const int ln   = lane & 15, quad = lane >> 4;
  const int wm   = w >> 1, wn = w & 1;
  const int m0 = blockIdx.y * 128, n0 = blockIdx.x * BN;

  const int srow = lane >> 2;               // 0..15
  const int schk = (lane & 3) * 8;          // 0,8,16,24 (shorts)
  const ushort* Ag0 = A + (size_t)(m0 + w * 32      + srow) * K + schk;
  const ushort* Ag1 = A + (size_t)(m0 + w * 32 + 16 + srow) * K + schk;
  const int brow = (BN == 128) ? w * 32 : w * 16;
  const ushort* Bg0 = B + (size_t)(n0 + brow + srow) * K + schk;
  const ushort* Bg1 = B + (size_t)(n0 + brow + 16 + srow) * K + schk; // BN==128 only
  short* lA0 = As + (w * 32) * 32;
  short* lA1 = As + (w * 32 + 16) * 32;
  short* lB0 = Bs + brow * 32;
  short* lB1 = Bs + (brow + 16) * 32;

  int aoff[4], boff[NI];
#pragma unroll
  for (int i = 0; i < 4; i++)
    aoff[i] = (wm * 64 + i * 16 + ln) * 32 + quad * 8;
#pragma unroll
  for (int i = 0; i < NI; i++)
    boff[i] = (wn * (BN / 2) + i * 16 + ln) * 32 + quad * 8;
  f32x4 acc[4][NI] = {};

  for (int kt = 0; kt < K; kt += 32) {
    __syncthreads();                        // WAR: prev tile reads done
    GLD_LDS16(Ag0 + kt, lA0);
    GLD_LDS16(Ag1 + kt, lA1);
    GLD_LDS16(Bg0 + kt, lB0);
    if (BN == 128) GLD_LDS16(Bg1 + kt, lB1);
    __syncthreads();                        // RAW: vmcnt drained at barrier
    short8 av[4], bv[NI];
#pragma unroll
    for (int i = 0; i < 4; i++) av[i] = *(const short8*)&As[aoff[i]];
#pragma unroll
    for (int i = 0; i < NI; i++) bv[i] = *(const short8*)&Bs[boff[i]];
#pragma unroll
    for (int mi = 0; mi < 4; mi++)
#pragma unroll
      for (int ni = 0; ni < NI; ni++)
        acc[mi][ni] = MFMA16(av[mi], bv[ni], acc[mi][ni]);
  }

  // Epilogue. C-layout: row = quad*4 + r, col = ln (verified m89/m91).
  if (MODE == 0) {
    ushort* Cq = (ushort*)Cv;
    if (n0 < 2048) {
      ushort* dst = Cq + (n0 < 1024 ? 0 : 4194304);   // q or k buffer
      const int nbase = (n0 < 1024) ? n0 : n0 - 1024;
#pragma unroll
      for (int mi = 0; mi < 4; mi++) {
        const int row = m0 + wm * 64 + mi * 16 + quad * 4;
#pragma unroll
        for (int ni = 0; ni < NI; ni++) {
          const int col = nbase + wn * (BN / 2) + ni * 16 + ln;
#pragma unroll
          for (int r = 0; r < 4; r++)
            dst[(size_t)(row + r) * 1024 + col] = f2bf(acc[mi][ni][r]);
        }
      }
    } else {
      ushort* vt = Cq + 8388608;                      // [bh][d][s] layout
#pragma unroll
      for (int mi = 0; mi < 4; mi++) {
        const int sm = m0 + wm * 64 + mi * 16 + quad * 4;   // token index
        const int b = sm >> 11, s = sm & 2047;
#pragma unroll
        for (int ni = 0; ni < NI; ni++) {
          const int nv = (n0 - 2048) + wn * (BN / 2) + ni * 16 + ln;
          const int bh = b * 16 + (nv >> 6), d = nv & 63;
          ushort4 u = make_ushort4(f2bf(acc[mi][ni][0]), f2bf(acc[mi][ni][1]),
                                   f2bf(acc[mi][ni][2]), f2bf(acc[mi][ni][3]));
          *(ushort4*)&vt[((size_t)bh * 64 + d) * 2048 + s] = u;
        }
      }
    }
  } else {
    float* C = (float*)Cv;
#pragma unroll
    for (int mi = 0; mi < 4; mi++) {
      const int row = m0 + wm * 64 + mi * 16 + quad * 4;
#pragma unroll
      for (int ni = 0; ni < NI; ni++) {
        const int col = n0 + wn * (BN / 2) + ni * 16 + ln;
#pragma unroll
        for (int r = 0; r < 4; r++)
          C[(size_t)(row + r) * 1024 + col] = acc[mi][ni][r];
      }
    }
  }
}

// ---------------------------------------------------------------------------
// Kernel 3: in-place interleaved RoPE on q,k via hardware v_sin/v_cos
// (revolutions domain, floorf range reduction) and exp2 for inv_freq.
// Q additionally scaled by attn_scale*log2e for the exp2-domain softmax.
// ---------------------------------------------------------------------------
__global__ __launch_bounds__(256) void ropek(ushort* __restrict__ qk) {
  const int g  = blockIdx.x * 256 + threadIdx.x;
  const int P0 = g << 2;
  const int mv = P0 >> 9;
  const int s  = mv & 2047;
  const int i0 = P0 & 31;
  const float scale = (mv < 4096) ? 0.04508422002778011f : 1.0f; // (1/32)*log2e
  const float sf = (float)s;
  short8 u = *(short8*)&qk[(size_t)P0 * 2];
  short8 ov;
#pragma unroll
  for (int t = 0; t < 4; t++) {
    // inv_freq = 10000^(-(i0+t)/32) = exp2(-(i0+t)*log2(1e4)/32)
    const float invf = __builtin_amdgcn_exp2f(-(float)(i0 + t) * 0.4152410118579865f);
    const float rev  = sf * invf * 0.15915494309189535f;   // angle in revolutions
    const float rr   = rev - floorf(rev);                  // [0,1)
    const float sn = __builtin_amdgcn_sinf(rr);            // sin(2*pi*rr)
    const float cs = __builtin_amdgcn_cosf(rr);
    const float x1 = bf2f((unsigned short)u[2 * t]);
    const float x2 = bf2f((unsigned short)u[2 * t + 1]);
    ov[2 * t]     = (short)f2bf((x1 * cs - x2 * sn) * scale);
    ov[2 * t + 1] = (short)f2bf((x1 * sn + x2 * cs) * scale);
  }
  *(short8*)&qk[(size_t)P0 * 2] = ov;
}

// ---------------------------------------------------------------------------
// Kernel 4 v5: causal-balanced flash attention + split-KV wave groups.
// Block x in [0,16) owns q-tiles jA=x and jB=31-x (33 tile-equivs, uniform).
// 512 thr = 8 waves = 2 groups; group g processes KV tiles t = 2i+g into its
// own Ks/Vs buffers -> critical path ~17 steps, 16 waves/CU (2 blocks/CU).
// Max-free softmax (|s'| bounded -> p=exp2(s') direct, no running max): the
// cross-group merge is PURELY ADDITIVE: o=oG0+oG1, l=lG0+lG1, out=o/l.
// Wave wg owns rows [16*wg,16*wg+16) of each q-tile; P via wave-private LDS.
// LDS 55296 B -> 2 blocks/CU.
// ---------------------------------------------------------------------------
__global__ __launch_bounds__(512, 4) void attnk(const ushort* __restrict__ q,
                                                const ushort* __restrict__ k,
                                                const ushort* __restrict__ vt,
                                                ushort* __restrict__ ctx) {
  __shared__ __align__(16) char smem[55296];
  short* KsB = (short*)smem;               // [2][64*72]
  short* VsB = (short*)(smem + 18432);     // [2][64*72]
  short* PsB = (short*)(smem + 36864);     // [8][16*72]
  // end-of-kernel merge aliases (over Ks/Vs region, after final barrier):
  float* OcA = (float*)smem;               // [64][64]
  float* OcB = (float*)(smem + 16384);     // [64][64]
  float* Lc  = (float*)(smem + 32768);     // [0..63]=lA, [64..127]=lB

  const int tid  = threadIdx.x;
  const int lane = tid & 63, w = tid >> 6;     // w in 0..7
  const int g = w >> 2, wg = w & 3;            // group, wave-in-group
  const int ln = lane & 15, quad = lane >> 4;
  const int x = blockIdx.x, bh = blockIdx.y;
  const int b = bh >> 4, h = bh & 15;
  const int jA = x, jB = 31 - x;
  short* Ks = KsB + g * 4608;
  short* Vs = VsB + g * 4608;
  short* Pw = PsB + w * 1152;

  // Q fragments (A-layout: m=ln, k=quad*8+j); wave wg -> rows j*64+wg*16+ln
  const size_t qbA = ((size_t)(b * 2048 + jA * 64 + wg * 16 + ln)) * 1024 + h * 64;
  const size_t qbB = ((size_t)(b * 2048 + jB * 64 + wg * 16 + ln)) * 1024 + h * 64;
  const short8 aqA0 = *(const short8*)&q[qbA + quad * 8];
  const short8 aqA1 = *(const short8*)&q[qbA + 32 + quad * 8];
  const short8 aqB0 = *(const short8*)&q[qbB + quad * 8];
  const short8 aqB1 = *(const short8*)&q[qbB + 32 + quad * 8];

  f32x4 oA[4] = {}, oB[4] = {};
  float lsA[4] = {0.f, 0.f, 0.f, 0.f}, lsB[4] = {0.f, 0.f, 0.f, 0.f};

  // staging: group's 256 threads cover a 64x64 tile as 512 short8 slots
  const int tg = tid & 255;
  const int r0 = tg >> 3, c0 = (tg & 7) * 8;   // rows 0..31
  const int r1 = r0 + 32, c1 = c0;             // rows 32..63
  const ushort* kg0 = k  + ((size_t)(b * 2048 + r0)) * 1024 + h * 64 + c0;
  const ushort* kg1 = k  + ((size_t)(b * 2048 + r1)) * 1024 + h * 64 + c1;
  const ushort* vg0 = vt + ((size_t)(bh * 64 + r0)) * 2048 + c0;
  const ushort* vg1 = vt + ((size_t)(bh * 64 + r1)) * 2048 + c1;
  const int wK0 = r0 * 72 + c0, wK1 = r1 * 72 + c1;

  const int nsteps = (jB >> 1) + 1;            // g=0 step count >= g=1's
  for (int i = 0; i < nsteps; ++i) {
    const int t = 2 * i + g;
    const bool act = (t <= jB);
    __syncthreads();                           // WAR vs previous compute
    if (act) {
      *(short8*)&Ks[wK0] = *(const short8*)(kg0 + (size_t)t * 65536);
      *(short8*)&Ks[wK1] = *(const short8*)(kg1 + (size_t)t * 65536);
      *(short8*)&Vs[wK0] = *(const short8*)(vg0 + t * 64);
      *(short8*)&Vs[wK1] = *(const short8*)(vg1 + t * 64);
    }
    __syncthreads();                           // RAW
    if (act) {
      const bool actA = (t <= jA);
      f32x4 scA[4], scB[4];
#pragma unroll
      for (int ct = 0; ct < 4; ct++) {
        const short8 bk0 = *(const short8*)&Ks[(ct * 16 + ln) * 72 + quad * 8];
        const short8 bk1 = *(const short8*)&Ks[(ct * 16 + ln) * 72 + 32 + quad * 8];
        f32x4 z = {0.f, 0.f, 0.f, 0.f};
        z = MFMA16(aqB0, bk0, z);
        z = MFMA16(aqB1, bk1, z);
        scB[ct] = z;
        if (actA) {
          f32x4 y = {0.f, 0.f, 0.f, 0.f};
          y = MFMA16(aqA0, bk0, y);
          y = MFMA16(aqA1, bk1, y);
          scA[ct] = y;
        }
      }
      if (t == jB) {                           // diag mask for tile B
#pragma unroll
        for (int ct = 0; ct < 4; ct++) {
          const int kv = (t << 6) + ct * 16 + ln;
#pragma unroll
          for (int r = 0; r < 4; r++)
            if (kv > jB * 64 + wg * 16 + quad * 4 + r) scB[ct][r] = -100000.0f;
        }
      }
      if (actA && t == jA) {                   // diag mask for tile A
#pragma unroll
        for (int ct = 0; ct < 4; ct++) {
          const int kv = (t << 6) + ct * 16 + ln;
#pragma unroll
          for (int r = 0; r < 4; r++)
            if (kv > jA * 64 + wg * 16 + quad * 4 + r) scA[ct][r] = -100000.0f;
        }
      }

      // V fragments once, shared by both q-tiles
      short8 bv0[4], bv1[4];
#pragma unroll
      for (int dt = 0; dt < 4; dt++) {
        bv0[dt] = *(const short8*)&Vs[(dt * 16 + ln) * 72 + quad * 8];
        bv1[dt] = *(const short8*)&Vs[(dt * 16 + ln) * 72 + 32 + quad * 8];
      }

      // ---- tile B: p = exp2(s'), accumulate directly (no rescale) ----
#pragma unroll
      for (int ct = 0; ct < 4; ct++)
#pragma unroll
        for (int r = 0; r < 4; r++) {
          const float p = __builtin_amdgcn_exp2f(scB[ct][r]);
          lsB[r] += p;
          Pw[(quad * 4 + r) * 72 + ct * 16 + ln] = (short)f2bf(p);
        }
      {
        const short8 ap0 = *(const short8*)&Pw[ln * 72 + quad * 8];
        const short8 ap1 = *(const short8*)&Pw[ln * 72 + 32 + quad * 8];
#pragma unroll
        for (int dt = 0; dt < 4; dt++) {
          oB[dt] = MFMA16(ap0, bv0[dt], oB[dt]);
          oB[dt] = MFMA16(ap1, bv1[dt], oB[dt]);
        }
      }
      // ---- tile A (reuses Pw; same-wave LDS ops are ordered) ----
      if (actA) {
#pragma unroll
        for (int ct = 0; ct < 4; ct++)
#pragma unroll
          for (int r = 0; r < 4; r++) {
            const float p = __builtin_amdgcn_exp2f(scA[ct][r]);
            lsA[r] += p;
            Pw[(quad * 4 + r) * 72 + ct * 16 + ln] = (short)f2bf(p);
          }
        const short8 ap0 = *(const short8*)&Pw[ln * 72 + quad * 8];
        const short8 ap1 = *(const short8*)&Pw[ln * 72 + 32 + quad * 8];
#pragma unroll
        for (int dt = 0; dt < 4; dt++) {
          oA[dt] = MFMA16(ap0, bv0[dt], oA[dt]);
          oA[dt] = MFMA16(ap1, bv1[dt], oA[dt]);
        }
      }
    }
  }

  // reduce per-lane l partials across the quad's 16 lanes
#pragma unroll
  for (int off = 1; off < 16; off <<= 1)
#pragma unroll
    for (int r = 0; r < 4; r++) {
      lsA[r] += __shfl_xor(lsA[r], off, 64);
      lsB[r] += __shfl_xor(lsB[r], off, 64);
    }

  __syncthreads();                             // loop LDS reads done (alias Oc*)
  if (g == 1) {                                // publish partials (additive)
    const int rl = wg * 16 + quad * 4;
#pragma unroll
    for (int dt = 0; dt < 4; dt++)
#pragma unroll
      for (int r = 0; r < 4; r++) {
        OcA[(rl + r) * 64 + dt * 16 + ln] = oA[dt][r];
        OcB[(rl + r) * 64 + dt * 16 + ln] = oB[dt][r];
      }
    if (ln == 0)
#pragma unroll
      for (int r = 0; r < 4; r++) {
        Lc[rl + r]      = lsA[r];
        Lc[64 + rl + r] = lsB[r];
      }
  }
  __syncthreads();
  if (g == 0) {                                // merge (add) + write ctx
#pragma unroll
    for (int r = 0; r < 4; r++) {
      const int rl = wg * 16 + quad * 4 + r;
      const float invA = 1.0f / (lsA[r] + Lc[rl]);
      const float invB = 1.0f / (lsB[r] + Lc[64 + rl]);
      const int rowA = jA * 64 + rl, rowB = jB * 64 + rl;
#pragma unroll
      for (int dt = 0; dt < 4; dt++) {
        ctx[((size_t)(b * 2048 + rowA)) * 1024 + h * 64 + dt * 16 + ln] =
            f2bf((oA[dt][r] + OcA[rl * 64 + dt * 16 + ln]) * invA);
        ctx[((size_t)(b * 2048 + rowB)) * 1024 + h * 64 + dt * 16 + ln] =
            f2bf((oB[dt][r] + OcB[rl * 64 + dt * 16 + ln]) * invB);
      }
    }
  }
}

// ---------------------------------------------------------------------------
// Workspace layout: [xb 8MB][w bf16 8MB][qb 8MB][kb 8MB][vtb 8MB][ctx 8MB]
// ---------------------------------------------------------------------------
extern "C" void kernel_launch(void* const* d_in, const int* in_sizes, int n_in,
                              void* d_out, int out_size, void* d_ws, size_t ws_size,
                              hipStream_t stream) {
  const float* x  = (const float*)d_in[0];
  const float* Wq = (const float*)d_in[1];
  const float* Wk = (const float*)d_in[2];
  const float* Wv = (const float*)d_in[3];
  const float* Wo = (const float*)d_in[4];
  float* out = (float*)d_out;
  char* ws = (char*)d_ws;

  ushort* xb  = (ushort*)(ws);
  ushort* wqb = (ushort*)(ws + (size_t)(8  << 20));
  ushort* qb  = (ushort*)(ws + (size_t)(16 << 20));
  ushort* kb  = (ushort*)(ws + (size_t)(24 << 20));
  ushort* vtb = (ushort*)(ws + (size_t)(32 << 20));
  ushort* ctx = (ushort*)(ws + (size_t)(40 << 20));

  cvt_all<<<8192, 256, 0, stream>>>(x, Wq, Wk, Wv, Wo, xb);
  gemm_bt<0, 128><<<dim3(24, 32), 256, 0, stream>>>(xb, wqb, (void*)qb, 1024);
  ropek<<<4096, 256, 0, stream>>>(qb);
  attnk<<<dim3(16, 32), 512, 0, stream>>>(qb, kb, vtb, ctx);
  gemm_bt<2, 64><<<dim3(16, 32), 256, 0, stream>>>(ctx, wqb + 3145728 /*wob*/, (void*)out, 1024);
}

// Round 6
// 206.231 us; speedup vs baseline: 1.1185x; 1.1185x over previous
//
#include <hip/hip_runtime.h>

// ---------------------------------------------------------------------------
// CovariateAttention: out = MHA_causal(rope(x@Wq^T), rope(x@Wk^T), x@Wv^T) @ Wo^T
// B=2, S=2048, E=d_attn=1024, H=16, hd=64. All GEMM-shaped work in bf16 MFMA.
// ---------------------------------------------------------------------------

typedef float  f32x4  __attribute__((ext_vector_type(4)));
typedef short  short8 __attribute__((ext_vector_type(8)));

#define MFMA16(a,b,c) __builtin_amdgcn_mfma_f32_16x16x32_bf16((a),(b),(c),0,0,0)
// async global->LDS DMA, 16B/lane; LDS dest = wave-uniform base + lane*16
#define GLD_LDS16(g, l)                                                        \
  __builtin_amdgcn_global_load_lds(                                            \
      (const __attribute__((address_space(1))) unsigned int*)(g),              \
      (__attribute__((address_space(3))) unsigned int*)(l), 16, 0, 0)

__device__ __forceinline__ unsigned short f2bf(float f) {
  unsigned int x = __float_as_uint(f);
  x += 0x7fffu + ((x >> 16) & 1u);          // RNE
  return (unsigned short)(x >> 16);
}
__device__ __forceinline__ float bf2f(unsigned short u) {
  return __uint_as_float(((unsigned int)u) << 16);
}

// ---------------------------------------------------------------------------
// Kernel 1: convert x (4M fp32) + Wq,Wk,Wv,Wo (1M each) to bf16 (contiguous).
// ---------------------------------------------------------------------------
__global__ __launch_bounds__(256) void cvt_all(const float* __restrict__ x,
                                               const float* __restrict__ wq,
                                               const float* __restrict__ wk,
                                               const float* __restrict__ wv,
                                               const float* __restrict__ wo,
                                               ushort* __restrict__ dst) {
  const int i = blockIdx.x * 256 + threadIdx.x;      // [0, 2M)
  const float* src;
  int off;
  if (i < 1048576) { src = x; off = i; }
  else {
    const int j = i - 1048576;
    const int wsel = j >> 18;
    off = j & 262143;
    src = (wsel == 0) ? wq : (wsel == 1) ? wk : (wsel == 2) ? wv : wo;
  }
  const float4 v = ((const float4*)src)[off];
  ushort4 o = make_ushort4(f2bf(v.x), f2bf(v.y), f2bf(v.z), f2bf(v.w));
  ((ushort4*)dst)[i] = o;
}

// ---------------------------------------------------------------------------
// GEMM (m97 pattern): C[m,n] = sum_k A[m,k]*B[n,k]. BM=128 x BN tile, BK=32,
// 256 thr = 4 waves (2x2), wave tile 64 x BN/2. global_load_lds width=16
// staging, unpadded LDS stride 32, 2-barrier K-loop.
// ---------------------------------------------------------------------------
template<int MODE, int BN>
__global__ __launch_bounds__(256) void gemm_bt(const ushort* __restrict__ A,
                                               const ushort* __restrict__ B,
                                               void* __restrict__ Cv,
                                               int K) {
  constexpr int NI = BN / 32;               // n-frags per wave (4 or 2)
  __shared__ __align__(16) short As[128 * 32];
  __shared__ __align__(16) short Bs[BN * 32];
  const int tid  = threadIdx.x;
  const int lane = tid & 63, w = tid >> 6;
  const int ln   = lane & 15, quad = lane >> 4;
  const int wm   = w >> 1, wn = w & 1;
  const int m0 = blockIdx.y * 128, n0 = blockIdx.x * BN;

  const int srow = lane >> 2;               // 0..15
  const int schk = (lane & 3) * 8;          // 0,8,16,24 (shorts)
  const ushort* Ag0 = A + (size_t)(m0 + w * 32      + srow) * K + schk;
  const ushort* Ag1 = A + (size_t)(m0 + w * 32 + 16 + srow) * K + schk;
  const int brow = (BN == 128) ? w * 32 : w * 16;
  const ushort* Bg0 = B + (size_t)(n0 + brow + srow) * K + schk;
  const ushort* Bg1 = B + (size_t)(n0 + brow + 16 + srow) * K + schk; // BN==128 only
  short* lA0 = As + (w * 32) * 32;
  short* lA1 = As + (w * 32 + 16) * 32;
  short* lB0 = Bs + brow * 32;
  short* lB1 = Bs + (brow + 16) * 32;

  int aoff[4], boff[NI];
#pragma unroll
  for (int i = 0; i < 4; i++)
    aoff[i] = (wm * 64 + i * 16 + ln) * 32 + quad * 8;
#pragma unroll
  for (int i = 0; i < NI; i++)
    boff[i] = (wn * (BN / 2) + i * 16 + ln) * 32 + quad * 8;
  f32x4 acc[4][NI] = {};

  for (int kt = 0; kt < K; kt += 32) {
    __syncthreads();                        // WAR: prev tile reads done
    GLD_LDS16(Ag0 + kt, lA0);
    GLD_LDS16(Ag1 + kt, lA1);
    GLD_LDS16(Bg0 + kt, lB0);
    if (BN == 128) GLD_LDS16(Bg1 + kt, lB1);
    __syncthreads();                        // RAW: vmcnt drained at barrier
    short8 av[4], bv[NI];
#pragma unroll
    for (int i = 0; i < 4; i++) av[i] = *(const short8*)&As[aoff[i]];
#pragma unroll
    for (int i = 0; i < NI; i++) bv[i] = *(const short8*)&Bs[boff[i]];
#pragma unroll
    for (int mi = 0; mi < 4; mi++)
#pragma unroll
      for (int ni = 0; ni < NI; ni++)
        acc[mi][ni] = MFMA16(av[mi], bv[ni], acc[mi][ni]);
  }

  // Epilogue. C-layout: row = quad*4 + r, col = ln (verified m89/m91).
  if (MODE == 0) {
    ushort* Cq = (ushort*)Cv;
    if (n0 < 2048) {
      ushort* dst = Cq + (n0 < 1024 ? 0 : 4194304);   // q or k buffer
      const int nbase = (n0 < 1024) ? n0 : n0 - 1024;
#pragma unroll
      for (int mi = 0; mi < 4; mi++) {
        const int row = m0 + wm * 64 + mi * 16 + quad * 4;
#pragma unroll
        for (int ni = 0; ni < NI; ni++) {
          const int col = nbase + wn * (BN / 2) + ni * 16 + ln;
#pragma unroll
          for (int r = 0; r < 4; r++)
            dst[(size_t)(row + r) * 1024 + col] = f2bf(acc[mi][ni][r]);
        }
      }
    } else {
      ushort* vt = Cq + 8388608;                      // [bh][d][s] layout
#pragma unroll
      for (int mi = 0; mi < 4; mi++) {
        const int sm = m0 + wm * 64 + mi * 16 + quad * 4;   // token index
        const int b = sm >> 11, s = sm & 2047;
#pragma unroll
        for (int ni = 0; ni < NI; ni++) {
          const int nv = (n0 - 2048) + wn * (BN / 2) + ni * 16 + ln;
          const int bh = b * 16 + (nv >> 6), d = nv & 63;
          ushort4 u = make_ushort4(f2bf(acc[mi][ni][0]), f2bf(acc[mi][ni][1]),
                                   f2bf(acc[mi][ni][2]), f2bf(acc[mi][ni][3]));
          *(ushort4*)&vt[((size_t)bh * 64 + d) * 2048 + s] = u;
        }
      }
    }
  } else {
    float* C = (float*)Cv;
#pragma unroll
    for (int mi = 0; mi < 4; mi++) {
      const int row = m0 + wm * 64 + mi * 16 + quad * 4;
#pragma unroll
      for (int ni = 0; ni < NI; ni++) {
        const int col = n0 + wn * (BN / 2) + ni * 16 + ln;
#pragma unroll
        for (int r = 0; r < 4; r++)
          C[(size_t)(row + r) * 1024 + col] = acc[mi][ni][r];
      }
    }
  }
}

// ---------------------------------------------------------------------------
// Kernel 3: in-place interleaved RoPE via hardware v_sin/v_cos (revolutions)
// and exp2. Q scaled by attn_scale*log2e for the exp2-domain softmax.
// ---------------------------------------------------------------------------
__global__ __launch_bounds__(256) void ropek(ushort* __restrict__ qk) {
  const int g  = blockIdx.x * 256 + threadIdx.x;
  const int P0 = g << 2;
  const int mv = P0 >> 9;
  const int s  = mv & 2047;
  const int i0 = P0 & 31;
  const float scale = (mv < 4096) ? 0.04508422002778011f : 1.0f; // (1/32)*log2e
  const float sf = (float)s;
  short8 u = *(short8*)&qk[(size_t)P0 * 2];
  short8 ov;
#pragma unroll
  for (int t = 0; t < 4; t++) {
    const float invf = __builtin_amdgcn_exp2f(-(float)(i0 + t) * 0.4152410118579865f);
    const float rev  = sf * invf * 0.15915494309189535f;   // angle in revolutions
    const float rr   = rev - floorf(rev);                  // [0,1)
    const float sn = __builtin_amdgcn_sinf(rr);            // sin(2*pi*rr)
    const float cs = __builtin_amdgcn_cosf(rr);
    const float x1 = bf2f((unsigned short)u[2 * t]);
    const float x2 = bf2f((unsigned short)u[2 * t + 1]);
    ov[2 * t]     = (short)f2bf((x1 * cs - x2 * sn) * scale);
    ov[2 * t + 1] = (short)f2bf((x1 * sn + x2 * cs) * scale);
  }
  *(short8*)&qk[(size_t)P0 * 2] = ov;
}

// ---------------------------------------------------------------------------
// Kernel 4 v6: causal-balanced flash attention, max-free softmax, split-KV by
// PARITY ACROSS BLOCKS (grid 16x32x2): block (x,bh,par) owns q-tiles jA=x,
// jB=31-x and KV tiles t ≡ par (mod 2), t <= j. Register layout identical to
// the measured-good v4 (256 thr, 4 waves, VGPR~100, NO launch-bounds pin —
// round 5's (512,4) pin caused a 156MB scratch-spill regression).
// Partials are purely additive (no running max): O (bf16) -> Opart (d_out as
// scratch, 16MB exactly), l (fp32) -> Lpart (ws+0, dead xb region).
// 1024 blocks -> 4 blocks/CU -> 16 waves/CU.
// ---------------------------------------------------------------------------
__global__ __launch_bounds__(256) void attnk(const ushort* __restrict__ q,
                                             const ushort* __restrict__ k,
                                             const ushort* __restrict__ vt,
                                             ushort* __restrict__ Opart,
                                             float* __restrict__ Lpart) {
  __shared__ __align__(16) short Ks[64 * 72];
  __shared__ __align__(16) short Vs[64 * 72];
  __shared__ __align__(16) short Ps[4 * 16 * 72];
  const int tid  = threadIdx.x;
  const int lane = tid & 63, w = tid >> 6;
  const int ln   = lane & 15, quad = lane >> 4;
  const int x = blockIdx.x, bh = blockIdx.y, par = blockIdx.z;
  const int b = bh >> 4, h = bh & 15;
  const int jA = x, jB = 31 - x;
  short* Pw = Ps + w * 1152;

  // Q fragments (A-layout: m=ln, k=quad*8+j); wave w -> rows j*64+w*16+ln
  const size_t qbA = ((size_t)(b * 2048 + jA * 64 + w * 16 + ln)) * 1024 + h * 64;
  const size_t qbB = ((size_t)(b * 2048 + jB * 64 + w * 16 + ln)) * 1024 + h * 64;
  const short8 aqA0 = *(const short8*)&q[qbA + quad * 8];
  const short8 aqA1 = *(const short8*)&q[qbA + 32 + quad * 8];
  const short8 aqB0 = *(const short8*)&q[qbB + quad * 8];
  const short8 aqB1 = *(const short8*)&q[qbB + 32 + quad * 8];

  f32x4 oA[4] = {}, oB[4] = {};
  float lsA[4] = {0.f, 0.f, 0.f, 0.f}, lsB[4] = {0.f, 0.f, 0.f, 0.f};

  // staging: 256 threads cover a 64x64 tile as 512 short8 slots
  const int s0 = tid, s1 = tid + 256;
  const int r0 = s0 >> 3, c0 = (s0 & 7) * 8;
  const int r1 = s1 >> 3, c1 = (s1 & 7) * 8;
  const ushort* kg0 = k  + ((size_t)(b * 2048 + r0)) * 1024 + h * 64 + c0;
  const ushort* kg1 = k  + ((size_t)(b * 2048 + r1)) * 1024 + h * 64 + c1;
  const ushort* vg0 = vt + ((size_t)(bh * 64 + r0)) * 2048 + c0;
  const ushort* vg1 = vt + ((size_t)(bh * 64 + r1)) * 2048 + c1;
  const int wK0 = r0 * 72 + c0, wK1 = r1 * 72 + c1;

  for (int t = par; t <= jB; t += 2) {
    __syncthreads();                      // WAR vs previous compute
    *(short8*)&Ks[wK0] = *(const short8*)(kg0 + (size_t)t * 65536);
    *(short8*)&Ks[wK1] = *(const short8*)(kg1 + (size_t)t * 65536);
    *(short8*)&Vs[wK0] = *(const short8*)(vg0 + t * 64);
    *(short8*)&Vs[wK1] = *(const short8*)(vg1 + t * 64);
    __syncthreads();                      // RAW

    const bool actA = (t <= jA);          // block-uniform
    f32x4 scA[4], scB[4];
#pragma unroll
    for (int ct = 0; ct < 4; ct++) {
      const short8 bk0 = *(const short8*)&Ks[(ct * 16 + ln) * 72 + quad * 8];
      const short8 bk1 = *(const short8*)&Ks[(ct * 16 + ln) * 72 + 32 + quad * 8];
      f32x4 z = {0.f, 0.f, 0.f, 0.f};
      z = MFMA16(aqB0, bk0, z);
      z = MFMA16(aqB1, bk1, z);
      scB[ct] = z;
      if (actA) {
        f32x4 y = {0.f, 0.f, 0.f, 0.f};
        y = MFMA16(aqA0, bk0, y);
        y = MFMA16(aqA1, bk1, y);
        scA[ct] = y;
      }
    }
    if (t == jB) {                        // diag mask for tile B
#pragma unroll
      for (int ct = 0; ct < 4; ct++) {
        const int kv = (t << 6) + ct * 16 + ln;
#pragma unroll
        for (int r = 0; r < 4; r++)
          if (kv > jB * 64 + w * 16 + quad * 4 + r) scB[ct][r] = -100000.0f;
      }
    }
    if (actA && t == jA) {                // diag mask for tile A
#pragma unroll
      for (int ct = 0; ct < 4; ct++) {
        const int kv = (t << 6) + ct * 16 + ln;
#pragma unroll
        for (int r = 0; r < 4; r++)
          if (kv > jA * 64 + w * 16 + quad * 4 + r) scA[ct][r] = -100000.0f;
      }
    }

    // V fragments once, shared by both q-tiles
    short8 bv0[4], bv1[4];
#pragma unroll
    for (int dt = 0; dt < 4; dt++) {
      bv0[dt] = *(const short8*)&Vs[(dt * 16 + ln) * 72 + quad * 8];
      bv1[dt] = *(const short8*)&Vs[(dt * 16 + ln) * 72 + 32 + quad * 8];
    }

    // ---- tile B: p = exp2(s'), accumulate directly (no rescale) ----
#pragma unroll
    for (int ct = 0; ct < 4; ct++)
#pragma unroll
      for (int r = 0; r < 4; r++) {
        const float p = __builtin_amdgcn_exp2f(scB[ct][r]);
        lsB[r] += p;
        Pw[(quad * 4 + r) * 72 + ct * 16 + ln] = (short)f2bf(p);
      }
    {
      const short8 ap0 = *(const short8*)&Pw[ln * 72 + quad * 8];
      const short8 ap1 = *(const short8*)&Pw[ln * 72 + 32 + quad * 8];
#pragma unroll
      for (int dt = 0; dt < 4; dt++) {
        oB[dt] = MFMA16(ap0, bv0[dt], oB[dt]);
        oB[dt] = MFMA16(ap1, bv1[dt], oB[dt]);
      }
    }
    // ---- tile A (reuses Pw; same-wave LDS ops are ordered) ----
    if (actA) {
#pragma unroll
      for (int ct = 0; ct < 4; ct++)
#pragma unroll
        for (int r = 0; r < 4; r++) {
          const float p = __builtin_amdgcn_exp2f(scA[ct][r]);
          lsA[r] += p;
          Pw[(quad * 4 + r) * 72 + ct * 16 + ln] = (short)f2bf(p);
        }
      const short8 ap0 = *(const short8*)&Pw[ln * 72 + quad * 8];
      const short8 ap1 = *(const short8*)&Pw[ln * 72 + 32 + quad * 8];
#pragma unroll
      for (int dt = 0; dt < 4; dt++) {
        oA[dt] = MFMA16(ap0, bv0[dt], oA[dt]);
        oA[dt] = MFMA16(ap1, bv1[dt], oA[dt]);
      }
    }
  }

  // reduce per-lane l partials across the quad's 16 lanes
#pragma unroll
  for (int off = 1; off < 16; off <<= 1)
#pragma unroll
    for (int r = 0; r < 4; r++) {
      lsA[r] += __shfl_xor(lsA[r], off, 64);
      lsB[r] += __shfl_xor(lsB[r], off, 64);
    }

  // write partials: Opart[pidx][tile][row][col] bf16, Lpart[pidx][tile][row] f32
  const size_t pidx = ((size_t)(x * 32 + bh)) * 2 + par;
  const size_t ob = pidx * 8192;
#pragma unroll
  for (int r = 0; r < 4; r++) {
    const int row = w * 16 + quad * 4 + r;
#pragma unroll
    for (int dt = 0; dt < 4; dt++) {
      Opart[ob + row * 64 + dt * 16 + ln]        = f2bf(oA[dt][r]);
      Opart[ob + 4096 + row * 64 + dt * 16 + ln] = f2bf(oB[dt][r]);
    }
    if (ln == 0) {
      Lpart[pidx * 128 + row]      = lsA[r];
      Lpart[pidx * 128 + 64 + row] = lsB[r];
    }
  }
}

// ---------------------------------------------------------------------------
// Kernel 5: additive merge of the two parity partials -> ctx bf16.
// Grid (16,32,2): block (x,bh,tau) handles q-tile j = tau?31-x:x.
// Thread: row = tid>>2, 16 cols starting at (tid&3)*16.
// ---------------------------------------------------------------------------
__global__ __launch_bounds__(256) void mergek(const ushort* __restrict__ Opart,
                                              const float* __restrict__ Lpart,
                                              ushort* __restrict__ ctx) {
  const int x = blockIdx.x, bh = blockIdx.y, tau = blockIdx.z;
  const int b = bh >> 4, h = bh & 15;
  const int j = tau ? 31 - x : x;
  const int tid = threadIdx.x;
  const int row = tid >> 2, c0 = (tid & 3) * 16;
  const size_t p0 = ((size_t)(x * 32 + bh)) * 2;
  const size_t base0 = p0 * 8192 + (size_t)tau * 4096 + row * 64 + c0;
  const size_t base1 = base0 + 8192;
  const float l = Lpart[p0 * 128 + tau * 64 + row] +
                  Lpart[(p0 + 1) * 128 + tau * 64 + row];
  const float inv = 1.0f / l;
  const short8 u0a = *(const short8*)&Opart[base0];
  const short8 u0b = *(const short8*)&Opart[base0 + 8];
  const short8 u1a = *(const short8*)&Opart[base1];
  const short8 u1b = *(const short8*)&Opart[base1 + 8];
  short8 oa, ob;
#pragma unroll
  for (int i = 0; i < 8; i++) {
    oa[i] = (short)f2bf((bf2f((unsigned short)u0a[i]) +
                         bf2f((unsigned short)u1a[i])) * inv);
    ob[i] = (short)f2bf((bf2f((unsigned short)u0b[i]) +
                         bf2f((unsigned short)u1b[i])) * inv);
  }
  const size_t dst = ((size_t)(b * 2048 + j * 64 + row)) * 1024 + h * 64 + c0;
  *(short8*)&ctx[dst]     = oa;
  *(short8*)&ctx[dst + 8] = ob;
}

// ---------------------------------------------------------------------------
// Workspace: [xb 8MB / Lpart 512KB after gemm0][w bf16 8MB][qb 8MB][kb 8MB]
//            [vtb 8MB][ctx 8MB].  Opart scratch = d_out (16MB, rewritten by
//            the final GEMM).
// ---------------------------------------------------------------------------
extern "C" void kernel_launch(void* const* d_in, const int* in_sizes, int n_in,
                              void* d_out, int out_size, void* d_ws, size_t ws_size,
                              hipStream_t stream) {
  const float* x  = (const float*)d_in[0];
  const float* Wq = (const float*)d_in[1];
  const float* Wk = (const float*)d_in[2];
  const float* Wv = (const float*)d_in[3];
  const float* Wo = (const float*)d_in[4];
  float* out = (float*)d_out;
  char* ws = (char*)d_ws;

  ushort* xb  = (ushort*)(ws);
  ushort* wqb = (ushort*)(ws + (size_t)(8  << 20));
  ushort* qb  = (ushort*)(ws + (size_t)(16 << 20));
  ushort* kb  = (ushort*)(ws + (size_t)(24 << 20));
  ushort* vtb = (ushort*)(ws + (size_t)(32 << 20));
  ushort* ctx = (ushort*)(ws + (size_t)(40 << 20));
  float*  lpart = (float*)(ws);            // reuses xb region (dead after gemm0)
  ushort* opart = (ushort*)d_out;          // 16MB scratch, rewritten by gemm2

  cvt_all<<<8192, 256, 0, stream>>>(x, Wq, Wk, Wv, Wo, xb);
  gemm_bt<0, 128><<<dim3(24, 32), 256, 0, stream>>>(xb, wqb, (void*)qb, 1024);
  ropek<<<4096, 256, 0, stream>>>(qb);
  attnk<<<dim3(16, 32, 2), 256, 0, stream>>>(qb, kb, vtb, opart, lpart);
  mergek<<<dim3(16, 32, 2), 256, 0, stream>>>(opart, lpart, ctx);
  gemm_bt<2, 64><<<dim3(16, 32), 256, 0, stream>>>(ctx, wqb + 3145728 /*wob*/, (void*)out, 1024);
}